// Round 4
// baseline (771.824 us; speedup 1.0000x reference)
//
#include <hip/hip_runtime.h>
#include <math.h>

// ---------------------------------------------------------------------------
// VectorQuantize fused kernel for MI355X (gfx950) — R3: 32-token blocks,
// 2048 blocks -> 8 blocks/CU (32 waves/CU) for latency hiding.
// Shapes: z[16][1024][4096] f32, cb[1024][8], proj dims 1024<->8.
// Outputs concat (floats): z_out (16*1024*4096) | commit[16] | cb_loss[16] |
//                          indices[16*4096] (as float) | z_e (16*8*4096)
// ---------------------------------------------------------------------------

namespace {
constexpr int kB  = 16;
constexpr int kD  = 1024;   // D_IN
constexpr int kT  = 4096;
constexpr int kCB = 1024;   // codebook size
constexpr int kC  = 8;      // codebook dim
constexpr float kEps = 1e-12f;

constexpr size_t N_ZOUT    = (size_t)kB * kD * kT;         // 67108864
constexpr size_t OFF_COMMIT = N_ZOUT;                      // +16
constexpr size_t OFF_CBL    = OFF_COMMIT + kB;             // +16
constexpr size_t OFF_IDX    = OFF_CBL + kB;                // +65536
constexpr size_t OFF_ZE     = OFF_IDX + (size_t)kB * kT;   // +524288

constexpr int kTok = 32;    // tokens per block
}

// Prep: weight-norm weights (transposed) + normalized codebook into ws.
__global__ void vq_prep(const float* __restrict__ in_v, const float* __restrict__ in_g,
                        const float* __restrict__ out_v, const float* __restrict__ out_g,
                        const float* __restrict__ cb,
                        float* __restrict__ w_in_t, float* __restrict__ w_out_t,
                        float* __restrict__ cb_n_t)
{
    __shared__ float red[4];
    const int blk = blockIdx.x;
    const int tid = threadIdx.x;
    if (blk < 8) {
        const int o = blk;
        float ss = 0.f;
        for (int d = tid; d < kD; d += 256) {
            float v = in_v[o * kD + d];
            ss = fmaf(v, v, ss);
        }
        #pragma unroll
        for (int off = 32; off; off >>= 1) ss += __shfl_xor(ss, off);
        if ((tid & 63) == 0) red[tid >> 6] = ss;
        __syncthreads();
        const float scale = in_g[o] / sqrtf(red[0] + red[1] + red[2] + red[3]);
        for (int d = tid; d < kD; d += 256)
            w_in_t[d * kC + o] = scale * in_v[o * kD + d];
    } else if (blk < 12) {
        const int r = (blk - 8) * 256 + tid;
        float4 a = reinterpret_cast<const float4*>(cb)[2 * r];
        float4 b = reinterpret_cast<const float4*>(cb)[2 * r + 1];
        float n = sqrtf(a.x*a.x + a.y*a.y + a.z*a.z + a.w*a.w +
                        b.x*b.x + b.y*b.y + b.z*b.z + b.w*b.w);
        float s = 1.f / fmaxf(n, kEps);
        a.x *= s; a.y *= s; a.z *= s; a.w *= s;
        b.x *= s; b.y *= s; b.z *= s; b.w *= s;
        reinterpret_cast<float4*>(cb_n_t)[2 * r]     = a;
        reinterpret_cast<float4*>(cb_n_t)[2 * r + 1] = b;
    } else {
        const int r = (blk - 12) * 256 + tid;
        float4 a = reinterpret_cast<const float4*>(out_v)[2 * r];
        float4 b = reinterpret_cast<const float4*>(out_v)[2 * r + 1];
        float n = sqrtf(a.x*a.x + a.y*a.y + a.z*a.z + a.w*a.w +
                        b.x*b.x + b.y*b.y + b.z*b.z + b.w*b.w);
        float s = out_g[r] / n;   // reference uses no eps here
        a.x *= s; a.y *= s; a.z *= s; a.w *= s;
        b.x *= s; b.y *= s; b.z *= s; b.w *= s;
        reinterpret_cast<float4*>(w_out_t)[2 * r]     = a;
        reinterpret_cast<float4*>(w_out_t)[2 * r + 1] = b;
    }
}

// Main fused kernel: block = 32 tokens, 256 threads = 4 waves.
// Thread roles: tg = tid&7 (owns tokens 4tg..4tg+3 via float4),
//               sl = tid>>3 (slice 0..31: 32 d-rows / 32 codes / 32 o-rows).
__global__ __launch_bounds__(256, 8)
void vq_main(const float* __restrict__ z,
             const float* __restrict__ in_b, const float* __restrict__ out_b,
             const float* __restrict__ cb,
             const float* __restrict__ w_in_t, const float* __restrict__ w_out_t,
             const float* __restrict__ cb_n_t,
             float* __restrict__ out)
{
    __shared__ float s_red[4][kC][kTok];   // 4 KB: per-wave partial z_e
    __shared__ float s_ze[kC][kTok];       // 1 KB
    __shared__ float s_zq[kC][kTok];       // 1 KB
    __shared__ float s_sim[32][kTok];      // 4 KB
    __shared__ int   s_idx[32][kTok];      // 4 KB

    const int tid = threadIdx.x;
    const int tg = tid & 7;             // token group (4 tokens)
    const int sl = tid >> 3;            // slice 0..31
    const int wv = tid >> 6;            // wave 0..3
    const int g0 = blockIdx.x * kTok;   // global token base
    const int b  = g0 >> 12;            // / kT
    const int t0 = g0 & (kT - 1);

    // ---------------- Phase A: z_e = w_in @ z + in_b ------------------------
    // slice sl covers d in [sl*32, sl*32+32); float4 = 4 tokens per load.
    const float* zp = z + ((size_t)b * kD + (size_t)sl * 32) * kT + t0 + 4 * tg;
    const float4* wq = reinterpret_cast<const float4*>(w_in_t) + (size_t)sl * 64;
    float acc[kC][4];
    #pragma unroll
    for (int c = 0; c < kC; c++)
        #pragma unroll
        for (int j = 0; j < 4; j++) acc[c][j] = 0.f;

    #pragma unroll 8
    for (int i = 0; i < 32; i++) {
        const float4 zv = *reinterpret_cast<const float4*>(zp + (size_t)i * kT);
        const float4 w0 = wq[2 * i];        // uniform within 8-lane group
        const float4 w1 = wq[2 * i + 1];
        const float zl[4] = {zv.x, zv.y, zv.z, zv.w};
        const float wl[kC] = {w0.x, w0.y, w0.z, w0.w, w1.x, w1.y, w1.z, w1.w};
        #pragma unroll
        for (int c = 0; c < kC; c++)
            #pragma unroll
            for (int j = 0; j < 4; j++)
                acc[c][j] = fmaf(zl[j], wl[c], acc[c][j]);
    }
    // reduce the wave's 8 slices in-register (lane bits 3..5 span them)
    #pragma unroll
    for (int c = 0; c < kC; c++)
        #pragma unroll
        for (int j = 0; j < 4; j++) {
            float v = acc[c][j];
            v += __shfl_xor(v, 8);
            v += __shfl_xor(v, 16);
            v += __shfl_xor(v, 32);
            acc[c][j] = v;
        }
    if ((tid & 56) == 0) {               // lanes 0-7 of each wave
        #pragma unroll
        for (int c = 0; c < kC; c++)
            #pragma unroll
            for (int j = 0; j < 4; j++) s_red[wv][c][4 * tg + j] = acc[c][j];
    }
    __syncthreads();

    // final cross-wave reduce: 256 outputs / 256 threads = 1 each
    {
        const int c = tid >> 5;          // 0..7
        const int t = tid & 31;
        s_ze[c][t] = s_red[0][c][t] + s_red[1][c][t] + s_red[2][c][t]
                   + s_red[3][c][t] + in_b[c];
    }
    __syncthreads();

    // ---------------- VQ: argmax of z_e . cb_n over codes -------------------
    // (== argmin of reference cosine distance; per-token terms constant)
    // slice sl covers codes [sl*32, sl*32+32); 4 tokens per thread.
    float zef[4][kC];
    #pragma unroll
    for (int j = 0; j < 4; j++)
        #pragma unroll
        for (int c = 0; c < kC; c++) zef[j][c] = s_ze[c][4 * tg + j];

    float best[4] = {-INFINITY, -INFINITY, -INFINITY, -INFINITY};
    int   bk[4]   = {sl * 32, sl * 32, sl * 32, sl * 32};
    const float4* cq = reinterpret_cast<const float4*>(cb_n_t) + (size_t)sl * 64;
    #pragma unroll 4
    for (int i = 0; i < 32; i++) {
        const float4 c0 = cq[2 * i];
        const float4 c1 = cq[2 * i + 1];
        const float cl[kC] = {c0.x, c0.y, c0.z, c0.w, c1.x, c1.y, c1.z, c1.w};
        #pragma unroll
        for (int j = 0; j < 4; j++) {
            float sim = zef[j][0] * cl[0];
            #pragma unroll
            for (int c = 1; c < kC; c++) sim = fmaf(zef[j][c], cl[c], sim);
            if (sim > best[j]) { best[j] = sim; bk[j] = sl * 32 + i; } // first max
        }
    }
    #pragma unroll
    for (int j = 0; j < 4; j++) {
        s_sim[sl][4 * tg + j] = best[j];
        s_idx[sl][4 * tg + j] = bk[j];
    }
    __syncthreads();

    // per-token finalize: lanes 0-31 of wave 0, one token each
    if (tid < kTok) {
        const int t = tid;
        float bs = s_sim[0][t];
        int   bi = s_idx[0][t];
        #pragma unroll
        for (int g = 1; g < 32; g++) {
            const float v = s_sim[g][t];
            if (v > bs) { bs = v; bi = s_idx[g][t]; }   // strict >: lower slice wins
        }
        out[OFF_IDX + (size_t)b * kT + t0 + t] = (float)bi;

        const float4 q0 = reinterpret_cast<const float4*>(cb)[2 * bi];
        const float4 q1 = reinterpret_cast<const float4*>(cb)[2 * bi + 1];
        const float zq[kC] = {q0.x, q0.y, q0.z, q0.w, q1.x, q1.y, q1.z, q1.w};

        float lsum = 0.f;
        #pragma unroll
        for (int c = 0; c < kC; c++) {
            s_zq[c][t] = zq[c];
            const float ze = s_ze[c][t];
            const float d = ze - zq[c];
            lsum = fmaf(d, d, lsum);
            out[OFF_ZE + (size_t)b * (kC * kT) + (size_t)c * kT + t0 + t] = ze;
        }
        #pragma unroll
        for (int off = 16; off; off >>= 1) lsum += __shfl_xor(lsum, off);
        if (tid == 0) {
            const float lv = lsum * (1.f / (kC * kT));
            atomicAdd(&out[OFF_COMMIT + b], lv);
            atomicAdd(&out[OFF_CBL + b], lv);            // identical forward value
        }
    }
    __syncthreads();

    // ---------------- Phase B: z_out = w_out @ z_q + out_b ------------------
    // slice sl covers o in [sl*32, sl*32+32); 4 tokens per thread (float4 store).
    float zqr[4][kC];
    #pragma unroll
    for (int j = 0; j < 4; j++)
        #pragma unroll
        for (int c = 0; c < kC; c++) zqr[j][c] = s_zq[c][4 * tg + j];

    const float4* wo = reinterpret_cast<const float4*>(w_out_t) + (size_t)sl * 64;
    const float*  bo = out_b + sl * 32;
    float* op = out + ((size_t)b * kD + (size_t)sl * 32) * kT + t0 + 4 * tg;
    #pragma unroll 8
    for (int i = 0; i < 32; i++) {
        const float4 w0 = wo[2 * i];            // uniform within 8-lane group
        const float4 w1 = wo[2 * i + 1];
        const float wl[kC] = {w0.x, w0.y, w0.z, w0.w, w1.x, w1.y, w1.z, w1.w};
        const float bias = bo[i];
        float rr[4];
        #pragma unroll
        for (int j = 0; j < 4; j++) {
            float v = bias;
            #pragma unroll
            for (int c = 0; c < kC; c++) v = fmaf(zqr[j][c], wl[c], v);
            rr[j] = v;
        }
        const float4 r = make_float4(rr[0], rr[1], rr[2], rr[3]);
        *reinterpret_cast<float4*>(op + (size_t)i * kT) = r;   // 128B per 8-lane group
    }
}

extern "C" void kernel_launch(void* const* d_in, const int* in_sizes, int n_in,
                              void* d_out, int out_size, void* d_ws, size_t ws_size,
                              hipStream_t stream) {
    const float* z     = (const float*)d_in[0];
    const float* in_v  = (const float*)d_in[1];
    const float* in_g  = (const float*)d_in[2];
    const float* in_b  = (const float*)d_in[3];
    const float* out_v = (const float*)d_in[4];
    const float* out_g = (const float*)d_in[5];
    const float* out_b = (const float*)d_in[6];
    const float* cb    = (const float*)d_in[7];
    float* out = (float*)d_out;

    float* w_in_t  = (float*)d_ws;               // [1024][8]
    float* w_out_t = w_in_t + (size_t)kD * kC;   // [1024][8]
    float* cb_n_t  = w_out_t + (size_t)kD * kC;  // [1024][8]

    vq_prep<<<16, 256, 0, stream>>>(in_v, in_g, out_v, out_g, cb,
                                    w_in_t, w_out_t, cb_n_t);
    // zero the loss accumulators (d_out is poisoned 0xAA before every launch)
    (void)hipMemsetAsync(out + OFF_COMMIT, 0, 2 * kB * sizeof(float), stream);
    vq_main<<<(kB * kT) / kTok, 256, 0, stream>>>(z, in_b, out_b, cb,
                                                  w_in_t, w_out_t, cb_n_t, out);
}

// Round 5
// 526.519 us; speedup vs baseline: 1.4659x; 1.4659x over previous
//
#include <hip/hip_runtime.h>
#include <math.h>

// ---------------------------------------------------------------------------
// VectorQuantize for MI355X (gfx950) — R4: two streaming kernels.
// R3 lesson: 128B lane-group accesses at 16KB stride caused 2x read
// amplification + write RMW (fetch 887MB, write 454MB). Keep >=256B groups.
// R2 lesson: fused read-phase/write-phase serialize behind barriers at
// 4 blocks/CU. Split: vq_encode (read-bound) + vq_out (write-bound).
// Outputs concat (floats): z_out (16*1024*4096) | commit[16] | cb_loss[16] |
//                          indices[16*4096] (as float) | z_e (16*8*4096)
// ---------------------------------------------------------------------------

namespace {
constexpr int kB  = 16;
constexpr int kD  = 1024;   // D_IN
constexpr int kT  = 4096;
constexpr int kCB = 1024;   // codebook size
constexpr int kC  = 8;      // codebook dim
constexpr float kEps = 1e-12f;

constexpr size_t N_ZOUT    = (size_t)kB * kD * kT;         // 67108864
constexpr size_t OFF_COMMIT = N_ZOUT;                      // +16
constexpr size_t OFF_CBL    = OFF_COMMIT + kB;             // +16
constexpr size_t OFF_IDX    = OFF_CBL + kB;                // +65536
constexpr size_t OFF_ZE     = OFF_IDX + (size_t)kB * kT;   // +524288
}

// Prep: weight-norm weights (transposed) + normalized codebook into ws.
__global__ void vq_prep(const float* __restrict__ in_v, const float* __restrict__ in_g,
                        const float* __restrict__ out_v, const float* __restrict__ out_g,
                        const float* __restrict__ cb,
                        float* __restrict__ w_in_t, float* __restrict__ w_out_t,
                        float* __restrict__ cb_n_t)
{
    __shared__ float red[4];
    const int blk = blockIdx.x;
    const int tid = threadIdx.x;
    if (blk < 8) {
        const int o = blk;
        float ss = 0.f;
        for (int d = tid; d < kD; d += 256) {
            float v = in_v[o * kD + d];
            ss = fmaf(v, v, ss);
        }
        #pragma unroll
        for (int off = 32; off; off >>= 1) ss += __shfl_xor(ss, off);
        if ((tid & 63) == 0) red[tid >> 6] = ss;
        __syncthreads();
        const float scale = in_g[o] / sqrtf(red[0] + red[1] + red[2] + red[3]);
        for (int d = tid; d < kD; d += 256)
            w_in_t[d * kC + o] = scale * in_v[o * kD + d];
    } else if (blk < 12) {
        const int r = (blk - 8) * 256 + tid;
        float4 a = reinterpret_cast<const float4*>(cb)[2 * r];
        float4 b = reinterpret_cast<const float4*>(cb)[2 * r + 1];
        float n = sqrtf(a.x*a.x + a.y*a.y + a.z*a.z + a.w*a.w +
                        b.x*b.x + b.y*b.y + b.z*b.z + b.w*b.w);
        float s = 1.f / fmaxf(n, kEps);
        a.x *= s; a.y *= s; a.z *= s; a.w *= s;
        b.x *= s; b.y *= s; b.z *= s; b.w *= s;
        reinterpret_cast<float4*>(cb_n_t)[2 * r]     = a;
        reinterpret_cast<float4*>(cb_n_t)[2 * r + 1] = b;
    } else {
        const int r = (blk - 12) * 256 + tid;
        float4 a = reinterpret_cast<const float4*>(out_v)[2 * r];
        float4 b = reinterpret_cast<const float4*>(out_v)[2 * r + 1];
        float n = sqrtf(a.x*a.x + a.y*a.y + a.z*a.z + a.w*a.w +
                        b.x*b.x + b.y*b.y + b.z*b.z + b.w*b.w);
        float s = out_g[r] / n;   // reference uses no eps here
        a.x *= s; a.y *= s; a.z *= s; a.w *= s;
        b.x *= s; b.y *= s; b.z *= s; b.w *= s;
        reinterpret_cast<float4*>(w_out_t)[2 * r]     = a;
        reinterpret_cast<float4*>(w_out_t)[2 * r + 1] = b;
    }
}

// Encode kernel: block = 64 tokens, 256 threads = 4 waves.
// tg = tid&15 (owns 4 tokens via float4 => 16 lanes * 16B = 256B/group),
// sl = tid>>4 (slice 0..15: 64 d-rows / 64 codes).
// Reads z once (268 MB); writes z_e + idx + zq (~4.5 MB); loss atomics.
__global__ __launch_bounds__(256)
void vq_encode(const float* __restrict__ z,
               const float* __restrict__ in_b,
               const float* __restrict__ cb,
               const float* __restrict__ w_in_t,
               const float* __restrict__ cb_n_t,
               float* __restrict__ zq_ws,
               float* __restrict__ out)
{
    __shared__ float s_red[4][kC][64];   // 8 KB: per-wave partial z_e
    __shared__ float s_ze[kC][64];       // 2 KB
    __shared__ float s_sim[16][64];      // 4 KB
    __shared__ int   s_idx[16][64];      // 4 KB

    const int tid = threadIdx.x;
    const int tg = tid & 15;            // token group (4 tokens)
    const int sl = tid >> 4;            // slice 0..15
    const int wv = tid >> 6;            // wave 0..3
    const int g0 = blockIdx.x * 64;     // global token base
    const int b  = g0 >> 12;            // / kT
    const int t0 = g0 & (kT - 1);

    // ---------------- Phase A: z_e = w_in @ z + in_b ------------------------
    const float* zp = z + ((size_t)b * kD + (size_t)sl * 64) * kT + t0 + 4 * tg;
    const float4* wq = reinterpret_cast<const float4*>(w_in_t) + (size_t)sl * 128;
    float acc[kC][4];
    #pragma unroll
    for (int c = 0; c < kC; c++)
        #pragma unroll
        for (int j = 0; j < 4; j++) acc[c][j] = 0.f;

    #pragma unroll 4
    for (int i = 0; i < 64; i++) {
        const float4 zv = *reinterpret_cast<const float4*>(zp + (size_t)i * kT); // 256B/group
        const float4 w0 = wq[2 * i];        // uniform within 16-lane group
        const float4 w1 = wq[2 * i + 1];
        const float zl[4] = {zv.x, zv.y, zv.z, zv.w};
        const float wl[kC] = {w0.x, w0.y, w0.z, w0.w, w1.x, w1.y, w1.z, w1.w};
        #pragma unroll
        for (int c = 0; c < kC; c++)
            #pragma unroll
            for (int j = 0; j < 4; j++)
                acc[c][j] = fmaf(zl[j], wl[c], acc[c][j]);
    }
    // reduce the wave's 4 slices in-register (lane bits 4..5 span them)
    #pragma unroll
    for (int c = 0; c < kC; c++)
        #pragma unroll
        for (int j = 0; j < 4; j++) {
            float v = acc[c][j];
            v += __shfl_xor(v, 16);
            v += __shfl_xor(v, 32);
            acc[c][j] = v;
        }
    if ((tid & 48) == 0) {               // lanes 0-15 of each wave
        #pragma unroll
        for (int c = 0; c < kC; c++)
            #pragma unroll
            for (int j = 0; j < 4; j++) s_red[wv][c][4 * tg + j] = acc[c][j];
    }
    __syncthreads();

    // final cross-wave reduce: 512 outputs / 256 threads = 2 each
    {
        const int c  = tid >> 5;         // 0..7
        const int t2 = (tid & 31) * 2;
        #pragma unroll
        for (int k = 0; k < 2; k++) {
            const int t = t2 + k;
            s_ze[c][t] = s_red[0][c][t] + s_red[1][c][t] + s_red[2][c][t]
                       + s_red[3][c][t] + in_b[c];
        }
    }
    __syncthreads();

    // ---------------- VQ: argmax of z_e . cb_n over codes -------------------
    // (== argmin of reference cosine distance; per-token terms constant)
    float zef[4][kC];
    #pragma unroll
    for (int j = 0; j < 4; j++)
        #pragma unroll
        for (int c = 0; c < kC; c++) zef[j][c] = s_ze[c][4 * tg + j];

    float best[4] = {-INFINITY, -INFINITY, -INFINITY, -INFINITY};
    int   bk[4]   = {sl * 64, sl * 64, sl * 64, sl * 64};
    const float4* cq = reinterpret_cast<const float4*>(cb_n_t) + (size_t)sl * 128;
    #pragma unroll 2
    for (int i = 0; i < 64; i++) {
        const float4 c0 = cq[2 * i];
        const float4 c1 = cq[2 * i + 1];
        const float cl[kC] = {c0.x, c0.y, c0.z, c0.w, c1.x, c1.y, c1.z, c1.w};
        #pragma unroll
        for (int j = 0; j < 4; j++) {
            float sim = zef[j][0] * cl[0];
            #pragma unroll
            for (int c = 1; c < kC; c++) sim = fmaf(zef[j][c], cl[c], sim);
            if (sim > best[j]) { best[j] = sim; bk[j] = sl * 64 + i; } // first max
        }
    }
    #pragma unroll
    for (int j = 0; j < 4; j++) {
        s_sim[sl][4 * tg + j] = best[j];
        s_idx[sl][4 * tg + j] = bk[j];
    }
    __syncthreads();

    // per-token finalize: wave 0, one token each
    if (tid < 64) {
        const int t = tid;
        float bs = s_sim[0][t];
        int   bi = s_idx[0][t];
        #pragma unroll
        for (int g = 1; g < 16; g++) {
            const float v = s_sim[g][t];
            if (v > bs) { bs = v; bi = s_idx[g][t]; }   // strict >: lower slice wins
        }
        out[OFF_IDX + (size_t)b * kT + t0 + t] = (float)bi;

        const float4 q0 = reinterpret_cast<const float4*>(cb)[2 * bi];
        const float4 q1 = reinterpret_cast<const float4*>(cb)[2 * bi + 1];
        const float zq[kC] = {q0.x, q0.y, q0.z, q0.w, q1.x, q1.y, q1.z, q1.w};

        float lsum = 0.f;
        #pragma unroll
        for (int c = 0; c < kC; c++) {
            const float ze = s_ze[c][t];
            const float d = ze - zq[c];
            lsum = fmaf(d, d, lsum);
            // 64 lanes * 4B = 256B coalesced per c
            out[OFF_ZE + (size_t)b * (kC * kT) + (size_t)c * kT + t0 + t] = ze;
            zq_ws[((size_t)b * kC + c) * kT + t0 + t] = zq[c];
        }
        #pragma unroll
        for (int off = 32; off; off >>= 1) lsum += __shfl_xor(lsum, off);
        if (tid == 0) {
            const float lv = lsum * (1.f / (kC * kT));
            atomicAdd(&out[OFF_COMMIT + b], lv);
            atomicAdd(&out[OFF_CBL + b], lv);            // identical forward value
        }
    }
}

// Out-projection kernel: pure write stream. One block-iter = one (b,o) row of
// 4096 tokens; thread -> float4 (4 tokens); 4 sub-iters of 256 float4.
// zq (2 MB) stays L2/L3-resident; w_out row uniform per block.
__global__ __launch_bounds__(256)
void vq_out(const float* __restrict__ zq_ws,
            const float* __restrict__ w_out_t, const float* __restrict__ out_b,
            float* __restrict__ out)
{
    const int tid = threadIdx.x;
    for (int row = blockIdx.x; row < kB * kD; row += gridDim.x) {
        const int b = row >> 10;
        const int o = row & (kD - 1);
        const float4 w0 = reinterpret_cast<const float4*>(w_out_t)[2 * o];
        const float4 w1 = reinterpret_cast<const float4*>(w_out_t)[2 * o + 1];
        const float wl[kC] = {w0.x, w0.y, w0.z, w0.w, w1.x, w1.y, w1.z, w1.w};
        const float bias = out_b[o];
        const float4* zqp = reinterpret_cast<const float4*>(zq_ws)
                          + (size_t)b * kC * (kT / 4);
        float4* op = reinterpret_cast<float4*>(out) + (size_t)row * (kT / 4);
        #pragma unroll
        for (int k = 0; k < 4; k++) {
            const int t4 = k * 256 + tid;           // float4 index in the row
            float q[kC][4];
            #pragma unroll
            for (int c = 0; c < kC; c++) {
                const float4 qv = zqp[c * (kT / 4) + t4];   // 1KB/wave, L2-hit
                q[c][0] = qv.x; q[c][1] = qv.y; q[c][2] = qv.z; q[c][3] = qv.w;
            }
            float rr[4];
            #pragma unroll
            for (int j = 0; j < 4; j++) {
                float v = bias;
                #pragma unroll
                for (int c = 0; c < kC; c++) v = fmaf(q[c][j], wl[c], v);
                rr[j] = v;
            }
            op[t4] = make_float4(rr[0], rr[1], rr[2], rr[3]);  // 1KB/wave store
        }
    }
}

extern "C" void kernel_launch(void* const* d_in, const int* in_sizes, int n_in,
                              void* d_out, int out_size, void* d_ws, size_t ws_size,
                              hipStream_t stream) {
    const float* z     = (const float*)d_in[0];
    const float* in_v  = (const float*)d_in[1];
    const float* in_g  = (const float*)d_in[2];
    const float* in_b  = (const float*)d_in[3];
    const float* out_v = (const float*)d_in[4];
    const float* out_g = (const float*)d_in[5];
    const float* out_b = (const float*)d_in[6];
    const float* cb    = (const float*)d_in[7];
    float* out = (float*)d_out;

    float* w_in_t  = (float*)d_ws;                // [1024][8]
    float* w_out_t = w_in_t + (size_t)kD * kC;    // [1024][8]
    float* cb_n_t  = w_out_t + (size_t)kD * kC;   // [1024][8]
    float* zq_ws   = cb_n_t + (size_t)kCB * kC;   // [16][8][4096]

    vq_prep<<<16, 256, 0, stream>>>(in_v, in_g, out_v, out_g, cb,
                                    w_in_t, w_out_t, cb_n_t);
    // zero the loss accumulators (d_out is poisoned 0xAA before every launch)
    (void)hipMemsetAsync(out + OFF_COMMIT, 0, 2 * kB * sizeof(float), stream);
    vq_encode<<<(kB * kT) / 64, 256, 0, stream>>>(z, in_b, cb, w_in_t, cb_n_t,
                                                  zq_ws, out);
    vq_out<<<2048, 256, 0, stream>>>(zq_ws, w_out_t, out_b, out);
}

// Round 8
// 520.462 us; speedup vs baseline: 1.4830x; 1.0116x over previous
//
#include <hip/hip_runtime.h>
#include <math.h>

// ---------------------------------------------------------------------------
// VectorQuantize for MI355X (gfx950) — R7 (= R5 resubmit; R5/R6 never ran:
// GPU acquisition timeouts).
// R3 lesson: keep >=256B contiguous per 16-lane group (128B => RMW + overfetch).
// R4 lesson: harness re-poison fill (1.08GB @6.5TB/s = 166us) dominates top-5;
//            vq_out re-read zq 2GB from L2; encode only 16 waves/CU.
// R5: encode 512 thr (32 waves/CU); out keeps q in regs, loops 64 o-rows/block.
// Outputs concat (floats): z_out (16*1024*4096) | commit[16] | cb_loss[16] |
//                          indices[16*4096] (as float) | z_e (16*8*4096)
// ---------------------------------------------------------------------------

namespace {
constexpr int kB  = 16;
constexpr int kD  = 1024;   // D_IN
constexpr int kT  = 4096;
constexpr int kCB = 1024;   // codebook size
constexpr int kC  = 8;      // codebook dim
constexpr float kEps = 1e-12f;

constexpr size_t N_ZOUT    = (size_t)kB * kD * kT;         // 67108864
constexpr size_t OFF_COMMIT = N_ZOUT;                      // +16
constexpr size_t OFF_CBL    = OFF_COMMIT + kB;             // +16
constexpr size_t OFF_IDX    = OFF_CBL + kB;                // +65536
constexpr size_t OFF_ZE     = OFF_IDX + (size_t)kB * kT;   // +524288
}

// Prep: weight-norm weights (transposed) + normalized codebook into ws.
__global__ void vq_prep(const float* __restrict__ in_v, const float* __restrict__ in_g,
                        const float* __restrict__ out_v, const float* __restrict__ out_g,
                        const float* __restrict__ cb,
                        float* __restrict__ w_in_t, float* __restrict__ w_out_t,
                        float* __restrict__ cb_n_t)
{
    __shared__ float red[4];
    const int blk = blockIdx.x;
    const int tid = threadIdx.x;
    if (blk < 8) {
        const int o = blk;
        float ss = 0.f;
        for (int d = tid; d < kD; d += 256) {
            float v = in_v[o * kD + d];
            ss = fmaf(v, v, ss);
        }
        #pragma unroll
        for (int off = 32; off; off >>= 1) ss += __shfl_xor(ss, off);
        if ((tid & 63) == 0) red[tid >> 6] = ss;
        __syncthreads();
        const float scale = in_g[o] / sqrtf(red[0] + red[1] + red[2] + red[3]);
        for (int d = tid; d < kD; d += 256)
            w_in_t[d * kC + o] = scale * in_v[o * kD + d];
    } else if (blk < 12) {
        const int r = (blk - 8) * 256 + tid;
        float4 a = reinterpret_cast<const float4*>(cb)[2 * r];
        float4 b = reinterpret_cast<const float4*>(cb)[2 * r + 1];
        float n = sqrtf(a.x*a.x + a.y*a.y + a.z*a.z + a.w*a.w +
                        b.x*b.x + b.y*b.y + b.z*b.z + b.w*b.w);
        float s = 1.f / fmaxf(n, kEps);
        a.x *= s; a.y *= s; a.z *= s; a.w *= s;
        b.x *= s; b.y *= s; b.z *= s; b.w *= s;
        reinterpret_cast<float4*>(cb_n_t)[2 * r]     = a;
        reinterpret_cast<float4*>(cb_n_t)[2 * r + 1] = b;
    } else {
        const int r = (blk - 12) * 256 + tid;
        float4 a = reinterpret_cast<const float4*>(out_v)[2 * r];
        float4 b = reinterpret_cast<const float4*>(out_v)[2 * r + 1];
        float n = sqrtf(a.x*a.x + a.y*a.y + a.z*a.z + a.w*a.w +
                        b.x*b.x + b.y*b.y + b.z*b.z + b.w*b.w);
        float s = out_g[r] / n;   // reference uses no eps here
        a.x *= s; a.y *= s; a.z *= s; a.w *= s;
        b.x *= s; b.y *= s; b.z *= s; b.w *= s;
        reinterpret_cast<float4*>(w_out_t)[2 * r]     = a;
        reinterpret_cast<float4*>(w_out_t)[2 * r + 1] = b;
    }
}

// Encode kernel: block = 64 tokens, 512 threads = 8 waves (32 waves/CU at
// 4 blocks/CU -> 100% occupancy target).
// tg = tid&15 (4 tokens via float4 => 16 lanes * 16B = 256B/group),
// sl = tid>>4 (slice 0..31: 32 d-rows / 32 codes each).
__global__ __launch_bounds__(512)
void vq_encode(const float* __restrict__ z,
               const float* __restrict__ in_b,
               const float* __restrict__ cb,
               const float* __restrict__ w_in_t,
               const float* __restrict__ cb_n_t,
               float* __restrict__ zq_ws,
               float* __restrict__ out)
{
    __shared__ float s_red[8][kC][64];   // 16 KB: per-wave partial z_e
    __shared__ float s_ze[kC][64];       // 2 KB
    __shared__ float s_sim[32][64];      // 8 KB
    __shared__ int   s_idx[32][64];      // 8 KB

    const int tid = threadIdx.x;        // 0..511
    const int tg = tid & 15;            // token group (4 tokens)
    const int sl = tid >> 4;            // slice 0..31
    const int wv = tid >> 6;            // wave 0..7
    const int g0 = blockIdx.x * 64;     // global token base
    const int b  = g0 >> 12;            // / kT
    const int t0 = g0 & (kT - 1);

    // ---------------- Phase A: z_e = w_in @ z + in_b ------------------------
    // slice sl covers d in [sl*32, sl*32+32)
    const float* zp = z + ((size_t)b * kD + (size_t)sl * 32) * kT + t0 + 4 * tg;
    const float4* wq = reinterpret_cast<const float4*>(w_in_t) + (size_t)sl * 64;
    float acc[kC][4];
    #pragma unroll
    for (int c = 0; c < kC; c++)
        #pragma unroll
        for (int j = 0; j < 4; j++) acc[c][j] = 0.f;

    #pragma unroll 8
    for (int i = 0; i < 32; i++) {
        const float4 zv = *reinterpret_cast<const float4*>(zp + (size_t)i * kT); // 256B/group
        const float4 w0 = wq[2 * i];        // uniform within 16-lane group
        const float4 w1 = wq[2 * i + 1];
        const float zl[4] = {zv.x, zv.y, zv.z, zv.w};
        const float wl[kC] = {w0.x, w0.y, w0.z, w0.w, w1.x, w1.y, w1.z, w1.w};
        #pragma unroll
        for (int c = 0; c < kC; c++)
            #pragma unroll
            for (int j = 0; j < 4; j++)
                acc[c][j] = fmaf(zl[j], wl[c], acc[c][j]);
    }
    // in-wave reduce over the wave's 4 slices (lane bits 4,5)
    #pragma unroll
    for (int c = 0; c < kC; c++)
        #pragma unroll
        for (int j = 0; j < 4; j++) {
            float v = acc[c][j];
            v += __shfl_xor(v, 16);
            v += __shfl_xor(v, 32);
            acc[c][j] = v;
        }
    if ((tid & 48) == 0) {               // lanes 0-15 of each wave
        #pragma unroll
        for (int c = 0; c < kC; c++)
            #pragma unroll
            for (int j = 0; j < 4; j++) s_red[wv][c][4 * tg + j] = acc[c][j];
    }
    __syncthreads();

    // cross-wave reduce: 512 outputs (8c x 64t) / 512 threads = 1 each
    {
        const int c = tid >> 6;          // 0..7
        const int t = tid & 63;
        float v = in_b[c];
        #pragma unroll
        for (int w = 0; w < 8; w++) v += s_red[w][c][t];
        s_ze[c][t] = v;
    }
    __syncthreads();

    // ---------------- VQ: argmax of z_e . cb_n over codes -------------------
    // (== argmin of reference cosine distance; per-token terms constant)
    // slice sl covers codes [sl*32, sl*32+32); 4 tokens per thread.
    float zef[4][kC];
    #pragma unroll
    for (int j = 0; j < 4; j++)
        #pragma unroll
        for (int c = 0; c < kC; c++) zef[j][c] = s_ze[c][4 * tg + j];

    float best[4] = {-INFINITY, -INFINITY, -INFINITY, -INFINITY};
    int   bk[4]   = {sl * 32, sl * 32, sl * 32, sl * 32};
    const float4* cq = reinterpret_cast<const float4*>(cb_n_t) + (size_t)sl * 64;
    #pragma unroll 4
    for (int i = 0; i < 32; i++) {
        const float4 c0 = cq[2 * i];
        const float4 c1 = cq[2 * i + 1];
        const float cl[kC] = {c0.x, c0.y, c0.z, c0.w, c1.x, c1.y, c1.z, c1.w};
        #pragma unroll
        for (int j = 0; j < 4; j++) {
            float sim = zef[j][0] * cl[0];
            #pragma unroll
            for (int c = 1; c < kC; c++) sim = fmaf(zef[j][c], cl[c], sim);
            if (sim > best[j]) { best[j] = sim; bk[j] = sl * 32 + i; } // first max
        }
    }
    #pragma unroll
    for (int j = 0; j < 4; j++) {
        s_sim[sl][4 * tg + j] = best[j];
        s_idx[sl][4 * tg + j] = bk[j];
    }
    __syncthreads();

    // per-token finalize: lanes 0-63 (wave 0), one token each
    if (tid < 64) {
        const int t = tid;
        float bs = s_sim[0][t];
        int   bi = s_idx[0][t];
        #pragma unroll
        for (int g = 1; g < 32; g++) {
            const float v = s_sim[g][t];
            if (v > bs) { bs = v; bi = s_idx[g][t]; }   // strict >: lower slice wins
        }
        out[OFF_IDX + (size_t)b * kT + t0 + t] = (float)bi;

        const float4 q0 = reinterpret_cast<const float4*>(cb)[2 * bi];
        const float4 q1 = reinterpret_cast<const float4*>(cb)[2 * bi + 1];
        const float zq[kC] = {q0.x, q0.y, q0.z, q0.w, q1.x, q1.y, q1.z, q1.w};

        float lsum = 0.f;
        #pragma unroll
        for (int c = 0; c < kC; c++) {
            const float ze = s_ze[c][t];
            const float d = ze - zq[c];
            lsum = fmaf(d, d, lsum);
            // 64 lanes * 4B = 256B coalesced per c
            out[OFF_ZE + (size_t)b * (kC * kT) + (size_t)c * kT + t0 + t] = ze;
            zq_ws[((size_t)b * kC + c) * kT + t0 + t] = zq[c];
        }
        #pragma unroll
        for (int off = 32; off; off >>= 1) lsum += __shfl_xor(lsum, off);
        if (tid == 0) {
            const float lv = lsum * (1.f / (kC * kT));
            atomicAdd(&out[OFF_COMMIT + b], lv);
            atomicAdd(&out[OFF_CBL + b], lv);            // identical forward value
        }
    }
}

// Out-projection: block = (b, token-chunk of 1024, o-group of 64).
// Thread keeps its 4 tokens' q[8] in REGISTERS and loops over 64 o-rows
// (w rows staged in LDS, broadcast reads). zq re-read: 32KB/block = 32MB total
// (was 2GB in R4). Stores: 1KB/wave contiguous, 4KB/block-row fully covered.
__global__ __launch_bounds__(256)
void vq_out(const float* __restrict__ zq_ws,
            const float* __restrict__ w_out_t, const float* __restrict__ out_b,
            float* __restrict__ out)
{
    __shared__ float s_w[64][kC + 1];    // pad to 9 floats: conflict-free fill
    __shared__ float s_bias[64];

    const int tid = threadIdx.x;
    const int blk = blockIdx.x;          // 1024 = 16b x 4tc x 16og
    const int b   = blk >> 6;
    const int tc  = (blk >> 4) & 3;      // token chunk (1024 tokens)
    const int og  = blk & 15;            // o-group (64 rows)

    if (tid < 64) {
        const int o = og * 64 + tid;
        const float4 w0 = reinterpret_cast<const float4*>(w_out_t)[2 * o];
        const float4 w1 = reinterpret_cast<const float4*>(w_out_t)[2 * o + 1];
        s_w[tid][0] = w0.x; s_w[tid][1] = w0.y; s_w[tid][2] = w0.z; s_w[tid][3] = w0.w;
        s_w[tid][4] = w1.x; s_w[tid][5] = w1.y; s_w[tid][6] = w1.z; s_w[tid][7] = w1.w;
        s_bias[tid] = out_b[o];
    }

    // thread's 4 tokens: float4 index tc*256 + tid within each (b,c) row
    const float4* zqp = reinterpret_cast<const float4*>(zq_ws)
                      + (size_t)b * kC * (kT / 4) + tc * 256 + tid;
    float q[kC][4];
    #pragma unroll
    for (int c = 0; c < kC; c++) {
        const float4 qv = zqp[c * (kT / 4)];        // 1KB/wave, one-time
        q[c][0] = qv.x; q[c][1] = qv.y; q[c][2] = qv.z; q[c][3] = qv.w;
    }
    __syncthreads();

    float* op = out + ((size_t)b * kD + (size_t)og * 64) * kT + tc * 1024 + 4 * tid;
    #pragma unroll 4
    for (int i = 0; i < 64; i++) {
        float wl[kC];
        #pragma unroll
        for (int c = 0; c < kC; c++) wl[c] = s_w[i][c];   // LDS broadcast
        const float bias = s_bias[i];
        float rr[4];
        #pragma unroll
        for (int j = 0; j < 4; j++) {
            float v = bias;
            #pragma unroll
            for (int c = 0; c < kC; c++) v = fmaf(q[c][j], wl[c], v);
            rr[j] = v;
        }
        *reinterpret_cast<float4*>(op + (size_t)i * kT) =
            make_float4(rr[0], rr[1], rr[2], rr[3]);       // 1KB/wave store
    }
}

extern "C" void kernel_launch(void* const* d_in, const int* in_sizes, int n_in,
                              void* d_out, int out_size, void* d_ws, size_t ws_size,
                              hipStream_t stream) {
    const float* z     = (const float*)d_in[0];
    const float* in_v  = (const float*)d_in[1];
    const float* in_g  = (const float*)d_in[2];
    const float* in_b  = (const float*)d_in[3];
    const float* out_v = (const float*)d_in[4];
    const float* out_g = (const float*)d_in[5];
    const float* out_b = (const float*)d_in[6];
    const float* cb    = (const float*)d_in[7];
    float* out = (float*)d_out;

    float* w_in_t  = (float*)d_ws;                // [1024][8]
    float* w_out_t = w_in_t + (size_t)kD * kC;    // [1024][8]
    float* cb_n_t  = w_out_t + (size_t)kD * kC;   // [1024][8]
    float* zq_ws   = cb_n_t + (size_t)kCB * kC;   // [16][8][4096]

    vq_prep<<<16, 256, 0, stream>>>(in_v, in_g, out_v, out_g, cb,
                                    w_in_t, w_out_t, cb_n_t);
    // zero the loss accumulators (d_out is poisoned 0xAA before every launch)
    (void)hipMemsetAsync(out + OFF_COMMIT, 0, 2 * kB * sizeof(float), stream);
    vq_encode<<<(kB * kT) / 64, 512, 0, stream>>>(z, in_b, cb, w_in_t, cb_n_t,
                                                  zq_ws, out);
    vq_out<<<1024, 256, 0, stream>>>(zq_ws, w_out_t, out_b, out);
}